// Round 4
// baseline (1532.459 us; speedup 1.0000x reference)
//
#include <hip/hip_runtime.h>
#include <stdint.h>

// out[ch][s] = sum_{v: sp[v]==s} x[ch][ht[v]] * w[v],  ch in [0,128)
//
// R1: atomic scatter wrote 768 MB -> binned by sphere (601us).
// R2: accum f32 gather bound -> bf16 xT (516us).
// R3: scatter_kernel is top (115us): 8B random writes over 12MB from 8 XCDs
//     -> 95MB WRITE (8x line amp) + 1.5M global cursor atomics.
// R4: two-stage blocked counting sort over 512 coarse buckets (s>>6):
//     per-(bucket,block) offsets precomputed (no global atomics), LDS reorder
//     so record writes leave in grouped runs. Fine sort eliminated: accum
//     takes one bucket (64 bins) per block, ds_add_f32 into acc[64][129],
//     writes `out` directly (kills hist/scan32k/transpose_out/outT/memset).

#define S_BINS   32768
#define NBUCKET  512          // coarse buckets
#define BINS     64           // fine bins per bucket (S_BINS / NBUCKET)
#define CHUNK    4096         // votes per sort block

__device__ __forceinline__ unsigned bf16_rne(float f) {
    unsigned u = __float_as_uint(f);
    return (u + 0x7FFFu + ((u >> 16) & 1u)) >> 16;   // round-nearest-even
}

// x [128][HW] f32 -> xTb [HW][64] u32; word cp = bf16(ch=cp) | bf16(ch=cp+64)<<16
// (pairing (cp, cp+64) so accum's two ds_add_f32 are bank-conflict-free)
__global__ void transpose_x_bf16_kernel(const float* __restrict__ x,
                                        uint32_t* __restrict__ xTb, int HW) {
    __shared__ float tile[64][129];
    const int ht0 = blockIdx.x * 64;
    const int tid = threadIdx.x;      // 256
    for (int e = tid; e < 128 * 64; e += 256) {
        const int ch = e >> 6, hl = e & 63;
        tile[hl][ch] = x[(size_t)ch * HW + ht0 + hl];
    }
    __syncthreads();
    for (int e = tid; e < 64 * 64; e += 256) {
        const int hl = e >> 6, cp = e & 63;
        const unsigned lo = bf16_rne(tile[hl][cp]);
        const unsigned hi = bf16_rne(tile[hl][cp + 64]);
        xTb[(size_t)(ht0 + hl) * 64 + cp] = lo | (hi << 16);
    }
}

// Stage 1: per-block histogram of coarse buckets.
// blockHist layout: [bucket][block]  (bucket-major for the scan)
__global__ void count_kernel(const int* __restrict__ sp,
                             int* __restrict__ blockHist, int V, int nblk) {
    __shared__ int h[NBUCKET];
    const int blk = blockIdx.x, t = threadIdx.x;   // 256 thr
    for (int i = t; i < NBUCKET; i += 256) h[i] = 0;
    __syncthreads();
    const int base = blk * CHUNK;
    const int end  = min(V, base + CHUNK);
    for (int v = base + t; v < end; v += 256)
        atomicAdd(&h[sp[v] >> 6], 1);
    __syncthreads();
    for (int i = t; i < NBUCKET; i += 256)
        blockHist[(size_t)i * nblk + blk] = h[i];
}

// Single block, 512 threads. blockHist -> per-(bucket,block) global start;
// bucketBase[b] = global start of bucket b (bucketBase[512] = V).
__global__ void scan_kernel(int* __restrict__ blockHist,
                            int* __restrict__ bucketBase, int nblk) {
    __shared__ int tot[NBUCKET];
    const int b = threadIdx.x;        // 512
    int* row = blockHist + (size_t)b * nblk;
    int sum = 0;
    for (int k = 0; k < nblk; ++k) sum += row[k];
    tot[b] = sum;
    __syncthreads();
    for (int off = 1; off < NBUCKET; off <<= 1) {
        const int add = (b >= off) ? tot[b - off] : 0;
        __syncthreads();
        tot[b] += add;
        __syncthreads();
    }
    const int base = (b == 0) ? 0 : tot[b - 1];
    bucketBase[b] = base;
    if (b == NBUCKET - 1) bucketBase[NBUCKET] = tot[NBUCKET - 1];
    int running = base;
    for (int k = 0; k < nblk; ++k) {
        const int c = row[k];
        row[k] = running;
        running += c;
    }
}

// Stage 2: re-read chunk, reorder into LDS grouped by bucket, dump in slot
// order (grouped runs -> coalesced-ish writes). No global atomics.
// record: x = ht | (s_local<<18)  (ht<2^18, s_local<64), y = w bits.
__global__ void reorder_kernel(const int* __restrict__ ht,
                               const int* __restrict__ sp,
                               const float* __restrict__ w,
                               const int* __restrict__ blockHist,
                               uint2* __restrict__ records, int V, int nblk) {
    __shared__ uint2 rec[CHUNK];
    __shared__ unsigned short bid[CHUNK];
    __shared__ int hist[NBUCKET], cur[NBUCKET], startB[NBUCKET], gbase[NBUCKET];
    __shared__ int psum[256];
    const int blk = blockIdx.x, t = threadIdx.x;   // 256 thr
    const int base = blk * CHUNK;
    const int end  = min(V, base + CHUNK);
    const int n    = end - base;
    for (int i = t; i < NBUCKET; i += 256) hist[i] = 0;
    __syncthreads();
    for (int v = base + t; v < end; v += 256)
        atomicAdd(&hist[sp[v] >> 6], 1);
    __syncthreads();
    // exclusive scan of 512 hist entries with 256 threads (pair trick)
    const int a0 = hist[2 * t], a1 = hist[2 * t + 1];
    psum[t] = a0 + a1;
    __syncthreads();
    for (int off = 1; off < 256; off <<= 1) {
        const int add = (t >= off) ? psum[t - off] : 0;
        __syncthreads();
        psum[t] += add;
        __syncthreads();
    }
    const int excl = (t == 0) ? 0 : psum[t - 1];
    startB[2 * t]     = excl;
    startB[2 * t + 1] = excl + a0;
    cur[2 * t] = 0;
    cur[2 * t + 1] = 0;
    gbase[2 * t]     = blockHist[(size_t)(2 * t) * nblk + blk];
    gbase[2 * t + 1] = blockHist[(size_t)(2 * t + 1) * nblk + blk];
    __syncthreads();
    // place into LDS grouped by bucket
    for (int v = base + t; v < end; v += 256) {
        const int s = sp[v];
        const int b = s >> 6, sl = s & 63;
        const int r = atomicAdd(&cur[b], 1);
        const int slot = startB[b] + r;
        rec[slot] = make_uint2((unsigned)ht[v] | ((unsigned)sl << 18),
                               __float_as_uint(w[v]));
        bid[slot] = (unsigned short)b;
    }
    __syncthreads();
    // dump in slot order -> grouped global runs
    for (int i = t; i < n; i += 256) {
        const int b = bid[i];
        records[gbase[b] + (i - startB[b])] = rec[i];
    }
}

// One block per coarse bucket. 512 thr = 8 waves x 64 lanes.
// Lane handles channels (lane, lane+64). LDS acc[64][129]: ds_add addr
// stride 1 across lanes (conflict-free); epilogue read stride 129 (conflict-
// free); writes out directly in final layout.
__global__ __launch_bounds__(512) void accum_kernel(
    const uint32_t* __restrict__ xTb, const uint2* __restrict__ records,
    const int* __restrict__ bucketBase, float* __restrict__ out) {
    __shared__ float acc[BINS][129];
    const int bkt  = blockIdx.x;
    const int t    = threadIdx.x;
    const int lane = t & 63;
    const int wv   = t >> 6;          // 0..7
    float* accf = &acc[0][0];
    for (int i = t; i < BINS * 129; i += 512) accf[i] = 0.f;
    __syncthreads();
    const int start = bucketBase[bkt];
    const int end   = bucketBase[bkt + 1];
    // 4-deep unroll: 4 independent rec->gather chains in flight per wave
    for (int k0 = start + wv * 4; k0 < end; k0 += 32) {
#pragma unroll
        for (int u = 0; u < 4; ++u) {
            const int k = k0 + u;
            if (k < end) {
                const uint2 r = records[k];          // wave-uniform -> s_load
                const int   h = r.x & 0x3FFFF;
                const int bin = (r.x >> 18) & 63;
                const float wt = __uint_as_float(r.y);
                const uint32_t u32 = xTb[(size_t)h * 64 + lane];
                atomicAdd(&acc[bin][lane], __uint_as_float(u32 << 16) * wt);
                atomicAdd(&acc[bin][lane + 64],
                          __uint_as_float(u32 & 0xFFFF0000u) * wt);
            }
        }
    }
    __syncthreads();
    // out[ch][bkt*64 + bin]
    for (int e = t; e < 128 * BINS; e += 512) {
        const int ch = e >> 6, bin = e & 63;
        out[(size_t)ch * S_BINS + bkt * BINS + bin] = acc[bin][ch];
    }
}

// ---- fallback (direct atomic, any shape) ----
__global__ void direct_kernel(const float* __restrict__ x,
                              const int* __restrict__ ht_idx,
                              const int* __restrict__ sp_idx,
                              const float* __restrict__ weight,
                              float* __restrict__ out, int V, int HW, int S,
                              int CH) {
    const int v = blockIdx.x * 2 + (threadIdx.x >> 7);
    if (v >= V) return;
    const int ch = threadIdx.x & 127;
    if (ch >= CH) return;
    atomicAdd(&out[(size_t)ch * S + sp_idx[v]],
              x[(size_t)ch * HW + ht_idx[v]] * weight[v]);
}

extern "C" void kernel_launch(void* const* d_in, const int* in_sizes, int n_in,
                              void* d_out, int out_size, void* d_ws, size_t ws_size,
                              hipStream_t stream) {
    const float* x  = (const float*)d_in[0];
    const int*   ht = (const int*)d_in[1];
    const int*   sp = (const int*)d_in[2];
    const float* w  = (const float*)d_in[3];
    float* out = (float*)d_out;

    const int HW = 512 * 512;
    const int CH = in_sizes[0] / HW;          // 128
    const int S  = out_size / CH;             // 32768
    const int V  = in_sizes[1];               // 1.5M
    const int nblk = (V + CHUNK - 1) / CHUNK; // 367

    const size_t xTb_bytes  = (size_t)CH * HW * sizeof(uint16_t);     // 64 MB
    const size_t rec_bytes  = (size_t)V * sizeof(uint2);              // 12 MB
    const size_t bh_bytes   = (size_t)NBUCKET * nblk * sizeof(int);   // ~750 KB
    const size_t bb_bytes   = (size_t)(NBUCKET + 1) * sizeof(int);
    const size_t need = xTb_bytes + rec_bytes + bh_bytes + bb_bytes;

    if (CH == 128 && S == S_BINS && ws_size >= need) {
        char* p = (char*)d_ws;
        uint32_t* xTb     = (uint32_t*)p;  p += xTb_bytes;
        uint2* records    = (uint2*)p;     p += rec_bytes;
        int* blockHist    = (int*)p;       p += bh_bytes;
        int* bucketBase   = (int*)p;

        transpose_x_bf16_kernel<<<HW / 64, 256, 0, stream>>>(x, xTb, HW);
        count_kernel<<<nblk, 256, 0, stream>>>(sp, blockHist, V, nblk);
        scan_kernel<<<1, NBUCKET, 0, stream>>>(blockHist, bucketBase, nblk);
        reorder_kernel<<<nblk, 256, 0, stream>>>(ht, sp, w, blockHist, records,
                                                 V, nblk);
        accum_kernel<<<NBUCKET, 512, 0, stream>>>(xTb, records, bucketBase, out);
    } else {
        hipMemsetAsync(out, 0, (size_t)out_size * sizeof(float), stream);
        direct_kernel<<<(V + 1) / 2, 256, 0, stream>>>(x, ht, sp, w, out, V, HW,
                                                       S, CH);
    }
}

// Round 5
// 409.124 us; speedup vs baseline: 3.7457x; 3.7457x over previous
//
#include <hip/hip_runtime.h>
#include <stdint.h>

// out[ch][s] = sum_{v: sp[v]==s} x[ch][ht[v]] * w[v],  ch in [0,128)
//
// R1: atomic scatter wrote 768 MB -> bin by sphere (601us).
// R2: accum f32 gather bound -> bf16 xT (516us).
// R3: scatter 8B-random writes: 95MB amp + per-vote cursor atomics (115us).
// R4 FAILED (1532us): accum had 512 blocks + dependent rec->gather global
//     chains (212 GB/s, latency-bound); scan read blockHist uncoalesced.
// R5: coarse sort to 1024 buckets (one cursor atomic per block-bucket, LDS-
//     grouped dump); accum = 1024 blocks x 8 waves, records staged+fine-
//     sorted in LDS (32 bins), register accumulation, 8-deep gather MLP,
//     writes out directly in final layout.

#define S_BINS   32768
#define NBUCKET  1024        // coarse buckets = s >> 5
#define BINS     32          // fine bins per bucket
#define CHUNK    2048        // votes per sort block
#define TILE     2048        // votes per accum tile
#define HT_BITS  18          // HW = 512*512 = 2^18

__device__ __forceinline__ unsigned bf16_rne(float f) {
    unsigned u = __float_as_uint(f);
    return (u + 0x7FFFu + ((u >> 16) & 1u)) >> 16;   // round-nearest-even
}

// x [128][HW] f32 -> xTb [HW][64] u32; word cp = bf16(ch=cp) | bf16(ch=cp+64)<<16
__global__ void transpose_x_bf16_kernel(const float* __restrict__ x,
                                        uint32_t* __restrict__ xTb, int HW) {
    __shared__ float tile[64][129];
    const int ht0 = blockIdx.x * 64;
    const int tid = threadIdx.x;      // 256
    for (int e = tid; e < 128 * 64; e += 256) {
        const int ch = e >> 6, hl = e & 63;
        tile[hl][ch] = x[(size_t)ch * HW + ht0 + hl];
    }
    __syncthreads();
    for (int e = tid; e < 64 * 64; e += 256) {
        const int hl = e >> 6, cp = e & 63;
        const unsigned lo = bf16_rne(tile[hl][cp]);
        const unsigned hi = bf16_rne(tile[hl][cp + 64]);
        xTb[(size_t)(ht0 + hl) * 64 + cp] = lo | (hi << 16);
    }
}

// per-block bucket histogram -> global bucketTot (atomic)
__global__ void bucket_count_kernel(const int* __restrict__ sp,
                                    int* __restrict__ bucketTot, int V) {
    __shared__ int h[NBUCKET];
    const int blk = blockIdx.x, t = threadIdx.x;   // 256
    for (int i = t; i < NBUCKET; i += 256) h[i] = 0;
    __syncthreads();
    const int base = blk * CHUNK, end = min(V, base + CHUNK);
    for (int v = base + t; v < end; v += 256) atomicAdd(&h[sp[v] >> 5], 1);
    __syncthreads();
    for (int i = t; i < NBUCKET; i += 256) {
        const int c = h[i];
        if (c) atomicAdd(&bucketTot[i], c);
    }
}

// 1 block, 1024 threads: exclusive scan of bucketTot -> bucketBase & cursor
__global__ void scan_base_kernel(const int* __restrict__ bucketTot,
                                 int* __restrict__ bucketBase,
                                 int* __restrict__ cursor) {
    __shared__ int tot[NBUCKET];
    const int b = threadIdx.x;
    tot[b] = bucketTot[b];
    __syncthreads();
    for (int off = 1; off < NBUCKET; off <<= 1) {
        const int add = (b >= off) ? tot[b - off] : 0;
        __syncthreads();
        tot[b] += add;
        __syncthreads();
    }
    const int base = (b == 0) ? 0 : tot[b - 1];
    bucketBase[b] = base;
    cursor[b]     = base;
    if (b == NBUCKET - 1) bucketBase[NBUCKET] = tot[b];   // == V
}

// group CHUNK votes by bucket in LDS, claim global room with ONE atomic per
// (block,bucket), dump grouped runs. record: x = ht | (s_local<<18), y = w.
__global__ void reorder_kernel(const int* __restrict__ ht,
                               const int* __restrict__ sp,
                               const float* __restrict__ w,
                               int* __restrict__ cursor,
                               uint2* __restrict__ records, int V) {
    __shared__ uint2 rec[CHUNK];
    __shared__ uint16_t bid[CHUNK];
    __shared__ int hist[NBUCKET], start[NBUCKET], cur[NBUCKET], gbase[NBUCKET];
    __shared__ int psum[256];
    const int blk = blockIdx.x, t = threadIdx.x;   // 256
    const int base = blk * CHUNK, end = min(V, base + CHUNK), n = end - base;
    for (int i = t; i < NBUCKET; i += 256) hist[i] = 0;
    __syncthreads();
    for (int v = base + t; v < end; v += 256) atomicAdd(&hist[sp[v] >> 5], 1);
    __syncthreads();
    // exclusive scan of 1024 hist entries with 256 threads (4 per thread)
    const int l0 = hist[4*t], l1 = hist[4*t+1], l2 = hist[4*t+2], l3 = hist[4*t+3];
    psum[t] = l0 + l1 + l2 + l3;
    __syncthreads();
    for (int off = 1; off < 256; off <<= 1) {
        const int add = (t >= off) ? psum[t - off] : 0;
        __syncthreads();
        psum[t] += add;
        __syncthreads();
    }
    int run = (t == 0) ? 0 : psum[t - 1];
    start[4*t]   = run; cur[4*t]   = run; run += l0;
    start[4*t+1] = run; cur[4*t+1] = run; run += l1;
    start[4*t+2] = run; cur[4*t+2] = run; run += l2;
    start[4*t+3] = run; cur[4*t+3] = run;
    if (l0) gbase[4*t]   = atomicAdd(&cursor[4*t],   l0);
    if (l1) gbase[4*t+1] = atomicAdd(&cursor[4*t+1], l1);
    if (l2) gbase[4*t+2] = atomicAdd(&cursor[4*t+2], l2);
    if (l3) gbase[4*t+3] = atomicAdd(&cursor[4*t+3], l3);
    __syncthreads();
    for (int v = base + t; v < end; v += 256) {
        const int s = sp[v];
        const int b = s >> 5, sl = s & 31;
        const int pos = atomicAdd(&cur[b], 1);
        rec[pos] = make_uint2((unsigned)ht[v] | ((unsigned)sl << HT_BITS),
                              __float_as_uint(w[v]));
        bid[pos] = (uint16_t)b;
    }
    __syncthreads();
    for (int i = t; i < n; i += 256) {
        const int b = bid[i];
        records[gbase[b] + (i - start[b])] = rec[i];
    }
}

// One block per bucket, 8 waves. Per TILE: stage records coalesced -> LDS,
// fine-sort into 32 bins in LDS, wave owns 4 bins, VGPR accumulation with
// 8-deep gather unroll. Epilogue writes out[ch][bkt*32+bin] directly.
__global__ __launch_bounds__(512) void accum_kernel(
    const uint32_t* __restrict__ xTb, const uint2* __restrict__ records,
    const int* __restrict__ bucketBase, float* __restrict__ out) {
    __shared__ uint2 sorted[TILE];                       // 16 KB
    __shared__ __align__(16) char rawbuf[BINS * 129 * 4];// 16.5 KB: raw recs / epilogue
    __shared__ int hist[BINS], off[BINS + 1], cur[BINS];
    uint2* raw = (uint2*)rawbuf;
    const int bkt = blockIdx.x, t = threadIdx.x;
    const int lane = t & 63, wv = t >> 6;                // 8 waves
    const int vstart = bucketBase[bkt], vend = bucketBase[bkt + 1];
    float a[4][2];
#pragma unroll
    for (int i = 0; i < 4; ++i) { a[i][0] = 0.f; a[i][1] = 0.f; }

    for (int tbase = vstart; tbase < vend; tbase += TILE) {
        const int n = min(TILE, vend - tbase);
        if (t < BINS) hist[t] = 0;
        __syncthreads();
        for (int i = t; i < n; i += 512) {               // stage + histogram
            const uint2 r = records[tbase + i];
            raw[i] = r;
            atomicAdd(&hist[(r.x >> HT_BITS) & 31], 1);
        }
        __syncthreads();
        if (t == 0) {                                    // tiny 32-entry scan
            int run = 0;
            for (int j = 0; j < BINS; ++j) { off[j] = run; cur[j] = run; run += hist[j]; }
            off[BINS] = run;
        }
        __syncthreads();
        for (int i = t; i < n; i += 512) {               // place sorted
            const uint2 r = raw[i];
            const int pos = atomicAdd(&cur[(r.x >> HT_BITS) & 31], 1);
            sorted[pos] = r;
        }
        __syncthreads();
        // wave wv owns bins 4*wv .. 4*wv+3 (all control wave-uniform)
#pragma unroll
        for (int bb = 0; bb < 4; ++bb) {
            const int f = wv * 4 + bb;
            const int s0 = off[f], s1 = off[f + 1];
            for (int k = s0; k < s1; k += 8) {
#pragma unroll
                for (int u = 0; u < 8; ++u) {
                    const int kk = k + u;
                    if (kk < s1) {
                        const uint2 r = sorted[kk];      // LDS broadcast
                        const uint32_t uu = xTb[(size_t)(r.x & 0x3FFFF) * 64 + lane];
                        const float wt = __uint_as_float(r.y);
                        a[bb][0] += __uint_as_float(uu << 16) * wt;
                        a[bb][1] += __uint_as_float(uu & 0xFFFF0000u) * wt;
                    }
                }
            }
        }
        __syncthreads();                                  // before LDS reuse
    }
    // epilogue: VGPR -> LDS (reuse raw region) -> out rows (128B runs)
    float* epi = (float*)rawbuf;                          // [32][129]
#pragma unroll
    for (int bb = 0; bb < 4; ++bb) {
        const int f = wv * 4 + bb;
        epi[f * 129 + lane]      = a[bb][0];
        epi[f * 129 + lane + 64] = a[bb][1];
    }
    __syncthreads();
    for (int i = t; i < 128 * BINS; i += 512) {
        const int ch = i >> 5, bin = i & 31;
        out[(size_t)ch * S_BINS + bkt * BINS + bin] = epi[bin * 129 + ch];
    }
}

// ---- fallback (direct atomic, any shape) ----
__global__ void direct_kernel(const float* __restrict__ x,
                              const int* __restrict__ ht_idx,
                              const int* __restrict__ sp_idx,
                              const float* __restrict__ weight,
                              float* __restrict__ out, int V, int HW, int S,
                              int CH) {
    const int v = blockIdx.x * 2 + (threadIdx.x >> 7);
    if (v >= V) return;
    const int ch = threadIdx.x & 127;
    if (ch >= CH) return;
    atomicAdd(&out[(size_t)ch * S + sp_idx[v]],
              x[(size_t)ch * HW + ht_idx[v]] * weight[v]);
}

extern "C" void kernel_launch(void* const* d_in, const int* in_sizes, int n_in,
                              void* d_out, int out_size, void* d_ws, size_t ws_size,
                              hipStream_t stream) {
    const float* x  = (const float*)d_in[0];
    const int*   ht = (const int*)d_in[1];
    const int*   sp = (const int*)d_in[2];
    const float* w  = (const float*)d_in[3];
    float* out = (float*)d_out;

    const int HW = 512 * 512;
    const int CH = in_sizes[0] / HW;          // 128
    const int S  = out_size / CH;             // 32768
    const int V  = in_sizes[1];               // 1.5M
    const int nblk = (V + CHUNK - 1) / CHUNK; // 733

    const size_t xTb_bytes = (size_t)CH * HW * sizeof(uint16_t);    // 64 MB
    const size_t rec_bytes = (size_t)V * sizeof(uint2);             // 12 MB
    const size_t tot_bytes = (size_t)NBUCKET * sizeof(int);
    const size_t bb_bytes  = (size_t)(NBUCKET + 1) * sizeof(int);
    const size_t cur_bytes = (size_t)NBUCKET * sizeof(int);
    const size_t need = xTb_bytes + rec_bytes + tot_bytes + bb_bytes + cur_bytes;

    if (CH == 128 && S == S_BINS && HW == (1 << HT_BITS) && ws_size >= need) {
        char* p = (char*)d_ws;
        uint32_t* xTb   = (uint32_t*)p;  p += xTb_bytes;
        uint2* records  = (uint2*)p;     p += rec_bytes;
        int* bucketTot  = (int*)p;       p += tot_bytes;
        int* bucketBase = (int*)p;       p += bb_bytes;
        int* cursor     = (int*)p;

        hipMemsetAsync(bucketTot, 0, tot_bytes, stream);
        transpose_x_bf16_kernel<<<HW / 64, 256, 0, stream>>>(x, xTb, HW);
        bucket_count_kernel<<<nblk, 256, 0, stream>>>(sp, bucketTot, V);
        scan_base_kernel<<<1, NBUCKET, 0, stream>>>(bucketTot, bucketBase, cursor);
        reorder_kernel<<<nblk, 256, 0, stream>>>(ht, sp, w, cursor, records, V);
        accum_kernel<<<NBUCKET, 512, 0, stream>>>(xTb, records, bucketBase, out);
    } else {
        hipMemsetAsync(out, 0, (size_t)out_size * sizeof(float), stream);
        direct_kernel<<<(V + 1) / 2, 256, 0, stream>>>(x, ht, sp, w, out, V, HW,
                                                       S, CH);
    }
}

// Round 7
// 317.690 us; speedup vs baseline: 4.8238x; 1.2878x over previous
//
#include <hip/hip_runtime.h>
#include <stdint.h>

// out[ch][s] = sum_{v: sp[v]==s} x[ch][ht[v]] * w[v],  ch in [0,128)
//
// R1: atomic scatter wrote 768 MB -> bin by sphere (601us).
// R2: accum f32 gather bound -> bf16 xT (516us).
// R3: scatter 8B-random writes: 95MB amp + per-vote cursor atomics (115us).
// R4 FAILED (1532us): accum latency-bound (dependent global chains).
// R5 (409us): 1024-bucket sort + LDS-staged accum.
// R6 FAILED (absmax 17): epilogue cross-half LDS combine was an intra-wave
//     race (mutually-exclusive predicates -> compiler sees no store->load dep).
// R7: same as R6 but halves combined in REGISTERS via __shfl_xor(.,32);
//     only half0 writes epilogue LDS. No cross-lane LDS without sync.

#define S_BINS   32768
#define NBUCKET  1024        // coarse buckets = s >> 5
#define BINS     32          // fine bins per bucket
#define CAP      2048        // record slots per bucket (mean 1465, +15 sigma)
#define CHUNK    4096        // votes per reorder block
#define HT_BITS  18          // HW = 512*512 = 2^18

__device__ __forceinline__ unsigned bf16_rne(float f) {
    unsigned u = __float_as_uint(f);
    return (u + 0x7FFFu + ((u >> 16) & 1u)) >> 16;   // round-nearest-even
}

// x [128][HW] f32 -> xTb [HW][64] u32; word cp = bf16(ch=cp) | bf16(ch=cp+64)<<16
__global__ void transpose_x_bf16_kernel(const float* __restrict__ x,
                                        uint32_t* __restrict__ xTb, int HW) {
    __shared__ float tile[64][129];
    const int ht0 = blockIdx.x * 64;
    const int tid = threadIdx.x;      // 256
    for (int e = tid; e < 128 * 64; e += 256) {
        const int ch = e >> 6, hl = e & 63;
        tile[hl][ch] = x[(size_t)ch * HW + ht0 + hl];
    }
    __syncthreads();
    for (int e = tid; e < 64 * 64; e += 256) {
        const int hl = e >> 6, cp = e & 63;
        const unsigned lo = bf16_rne(tile[hl][cp]);
        const unsigned hi = bf16_rne(tile[hl][cp + 64]);
        xTb[(size_t)(ht0 + hl) * 64 + cp] = lo | (hi << 16);
    }
}

__global__ void init_kernel(int* __restrict__ cursor, int* __restrict__ spillCnt) {
    const int t = threadIdx.x;        // 1024
    cursor[t] = t * CAP;
    if (t == 0) *spillCnt = 0;
}

// Group CHUNK votes by bucket in LDS, claim room with ONE atomic per
// (block,bucket), dump grouped runs (avg 4 recs = 32B).
// record: x = ht | (s_local<<18)  (ht<2^18, s_local<32), y = w bits.
__global__ __launch_bounds__(512) void reorder_kernel(
    const int* __restrict__ ht, const int* __restrict__ sp,
    const float* __restrict__ w, int* __restrict__ cursor,
    uint2* __restrict__ records, uint2* __restrict__ spillRec,
    int* __restrict__ spillBkt, int* __restrict__ spillCnt, int V) {
    __shared__ uint2 rec[CHUNK];                       // 32 KB
    __shared__ uint16_t bid[CHUNK];                    // 8 KB
    __shared__ int hist[NBUCKET], start[NBUCKET], cur[NBUCKET], gbase[NBUCKET];
    __shared__ int psum[512];
    const int blk = blockIdx.x, t = threadIdx.x;       // 512
    const int base = blk * CHUNK, end = min(V, base + CHUNK), n = end - base;
    hist[2 * t] = 0; hist[2 * t + 1] = 0;
    __syncthreads();
    for (int v = base + t; v < end; v += 512) atomicAdd(&hist[sp[v] >> 5], 1);
    __syncthreads();
    // exclusive scan of 1024 hist entries with 512 threads (2 per thread)
    const int l0 = hist[2 * t], l1 = hist[2 * t + 1];
    psum[t] = l0 + l1;
    __syncthreads();
    for (int off = 1; off < 512; off <<= 1) {
        const int add = (t >= off) ? psum[t - off] : 0;
        __syncthreads();
        psum[t] += add;
        __syncthreads();
    }
    int run = (t == 0) ? 0 : psum[t - 1];
    start[2 * t]     = run; cur[2 * t]     = run; run += l0;
    start[2 * t + 1] = run; cur[2 * t + 1] = run;
    if (l0) gbase[2 * t]     = atomicAdd(&cursor[2 * t],     l0);
    if (l1) gbase[2 * t + 1] = atomicAdd(&cursor[2 * t + 1], l1);
    __syncthreads();
    for (int v = base + t; v < end; v += 512) {
        const int s = sp[v];
        const int b = s >> 5, sl = s & 31;
        const int pos = atomicAdd(&cur[b], 1);
        rec[pos] = make_uint2((unsigned)ht[v] | ((unsigned)sl << HT_BITS),
                              __float_as_uint(w[v]));
        bid[pos] = (uint16_t)b;
    }
    __syncthreads();
    for (int i = t; i < n; i += 512) {
        const int b = bid[i];
        const int slot = gbase[b] + (i - start[b]);
        if (slot < (b + 1) * CAP) {
            records[slot] = rec[i];
        } else {                                        // overflow: spill (cold)
            const int pos = atomicAdd(spillCnt, 1);
            spillRec[pos] = rec[i];
            spillBkt[pos] = b;
        }
    }
}

// One block per bucket, 8 waves x 64 lanes. Records staged+fine-sorted in LDS
// (32 bins); wave owns 4 bins; HALF-WAVE processes one vote (lane hl loads
// dwordx2 = channels {2hl, 2hl+64, 2hl+1, 2hl+65}); halves combined via
// __shfl_xor(.,32) in registers (race-free), half0 writes epilogue.
__global__ __launch_bounds__(512) void accum_kernel(
    const uint32_t* __restrict__ xTb, const uint2* __restrict__ records,
    const int* __restrict__ cursor, float* __restrict__ out) {
    __shared__ uint2 sorted[CAP];                        // 16 KB
    __shared__ __align__(16) char rawbuf[BINS * 129 * 4];// 16.5 KB raw/epilogue
    __shared__ int hist[BINS], off[BINS + 1], cur[BINS];
    uint2* raw = (uint2*)rawbuf;
    const uint2* xTb2 = (const uint2*)xTb;               // [HW][32] uint2 rows
    const int bkt = blockIdx.x, t = threadIdx.x;
    const int lane = t & 63, wv = t >> 6;                // 8 waves
    const int half = lane >> 5, hl = lane & 31;
    const int n = min(cursor[bkt] - bkt * CAP, CAP);
    const int rbase = bkt * CAP;
    float a[4][4];
#pragma unroll
    for (int i = 0; i < 4; ++i)
#pragma unroll
        for (int j = 0; j < 4; ++j) a[i][j] = 0.f;

    if (t < BINS) hist[t] = 0;
    __syncthreads();
    for (int i = t; i < n; i += 512) {                   // stage + histogram
        const uint2 r = records[rbase + i];
        raw[i] = r;
        atomicAdd(&hist[(r.x >> HT_BITS) & 31], 1);
    }
    __syncthreads();
    if (t == 0) {                                        // tiny 32-entry scan
        int run = 0;
        for (int j = 0; j < BINS; ++j) { off[j] = run; cur[j] = run; run += hist[j]; }
        off[BINS] = run;
    }
    __syncthreads();
    for (int i = t; i < n; i += 512) {                   // place sorted
        const uint2 r = raw[i];
        const int pos = atomicAdd(&cur[(r.x >> HT_BITS) & 31], 1);
        sorted[pos] = r;
    }
    __syncthreads();
#pragma unroll
    for (int bb = 0; bb < 4; ++bb) {                     // wave-uniform control
        const int f = wv * 4 + bb;
        const int s0 = off[f], s1 = off[f + 1];
        for (int k = s0; k < s1; k += 16) {              // 8-deep x 2 votes
#pragma unroll
            for (int u = 0; u < 8; ++u) {
                const int kk = k + 2 * u + half;
                if (kk < s1) {
                    const uint2 r = sorted[kk];          // 2-addr LDS broadcast
                    const uint2 g = xTb2[(size_t)(r.x & 0x3FFFF) * 32 + hl];
                    const float wt = __uint_as_float(r.y);
                    a[bb][0] += __uint_as_float(g.x << 16) * wt;
                    a[bb][1] += __uint_as_float(g.x & 0xFFFF0000u) * wt;
                    a[bb][2] += __uint_as_float(g.y << 16) * wt;
                    a[bb][3] += __uint_as_float(g.y & 0xFFFF0000u) * wt;
                }
            }
        }
    }
    // combine half-waves in registers: lane <-> lane^32 (race-free, full wave)
#pragma unroll
    for (int bb = 0; bb < 4; ++bb)
#pragma unroll
        for (int j = 0; j < 4; ++j)
            a[bb][j] += __shfl_xor(a[bb][j], 32);
    __syncthreads();                                     // before LDS reuse
    // epilogue: half0 lanes hold full sums -> LDS -> out rows (128B runs)
    float* epi = (float*)rawbuf;                         // [32][129]
    if (half == 0) {
#pragma unroll
        for (int bb = 0; bb < 4; ++bb) {
            const int f = wv * 4 + bb;
            epi[f * 129 + 2 * hl]      = a[bb][0];
            epi[f * 129 + 2 * hl + 64] = a[bb][1];
            epi[f * 129 + 2 * hl + 1]  = a[bb][2];
            epi[f * 129 + 2 * hl + 65] = a[bb][3];
        }
    }
    __syncthreads();
    for (int i = t; i < 128 * BINS; i += 512) {
        const int ch = i >> 5, bin = i & 31;
        out[(size_t)ch * S_BINS + bkt * BINS + bin] = epi[bin * 129 + ch];
    }
}

// Spilled votes (cold): atomicAdd into out on top of accum's exact sums.
__global__ void spill_kernel(const uint32_t* __restrict__ xTb,
                             const uint2* __restrict__ spillRec,
                             const int* __restrict__ spillBkt,
                             const int* __restrict__ spillCnt,
                             float* __restrict__ out) {
    const int cnt = *spillCnt;
    const long total = (long)cnt * 64;
    for (long u = (long)blockIdx.x * blockDim.x + threadIdx.x; u < total;
         u += (long)gridDim.x * blockDim.x) {
        const int i  = (int)(u >> 6);
        const int cp = (int)(u & 63);
        const uint2 r = spillRec[i];
        const int s = (spillBkt[i] << 5) | ((r.x >> HT_BITS) & 31);
        const uint32_t g = xTb[(size_t)(r.x & 0x3FFFF) * 64 + cp];
        const float wt = __uint_as_float(r.y);
        atomicAdd(&out[(size_t)cp * S_BINS + s],
                  __uint_as_float(g << 16) * wt);
        atomicAdd(&out[(size_t)(cp + 64) * S_BINS + s],
                  __uint_as_float(g & 0xFFFF0000u) * wt);
    }
}

// ---- fallback (direct atomic, any shape) ----
__global__ void direct_kernel(const float* __restrict__ x,
                              const int* __restrict__ ht_idx,
                              const int* __restrict__ sp_idx,
                              const float* __restrict__ weight,
                              float* __restrict__ out, int V, int HW, int S,
                              int CH) {
    const int v = blockIdx.x * 2 + (threadIdx.x >> 7);
    if (v >= V) return;
    const int ch = threadIdx.x & 127;
    if (ch >= CH) return;
    atomicAdd(&out[(size_t)ch * S + sp_idx[v]],
              x[(size_t)ch * HW + ht_idx[v]] * weight[v]);
}

extern "C" void kernel_launch(void* const* d_in, const int* in_sizes, int n_in,
                              void* d_out, int out_size, void* d_ws, size_t ws_size,
                              hipStream_t stream) {
    const float* x  = (const float*)d_in[0];
    const int*   ht = (const int*)d_in[1];
    const int*   sp = (const int*)d_in[2];
    const float* w  = (const float*)d_in[3];
    float* out = (float*)d_out;

    const int HW = 512 * 512;
    const int CH = in_sizes[0] / HW;          // 128
    const int S  = out_size / CH;             // 32768
    const int V  = in_sizes[1];               // 1.5M
    const int nblk = (V + CHUNK - 1) / CHUNK; // 367

    const size_t xTb_bytes = (size_t)CH * HW * sizeof(uint16_t);    // 64 MB
    const size_t rec_bytes = (size_t)NBUCKET * CAP * sizeof(uint2); // 16 MB
    const size_t spr_bytes = (size_t)V * sizeof(uint2);             // 12 MB
    const size_t spb_bytes = (size_t)V * sizeof(int);               // 6 MB
    const size_t cur_bytes = (size_t)NBUCKET * sizeof(int);
    const size_t cnt_bytes = 64;
    const size_t need = xTb_bytes + rec_bytes + spr_bytes + spb_bytes +
                        cur_bytes + cnt_bytes;

    if (CH == 128 && S == S_BINS && HW == (1 << HT_BITS) && ws_size >= need) {
        char* p = (char*)d_ws;
        uint32_t* xTb  = (uint32_t*)p;  p += xTb_bytes;
        uint2* records = (uint2*)p;     p += rec_bytes;
        uint2* spillRec= (uint2*)p;     p += spr_bytes;
        int* spillBkt  = (int*)p;       p += spb_bytes;
        int* cursor    = (int*)p;       p += cur_bytes;
        int* spillCnt  = (int*)p;

        init_kernel<<<1, NBUCKET, 0, stream>>>(cursor, spillCnt);
        transpose_x_bf16_kernel<<<HW / 64, 256, 0, stream>>>(x, xTb, HW);
        reorder_kernel<<<nblk, 512, 0, stream>>>(ht, sp, w, cursor, records,
                                                 spillRec, spillBkt, spillCnt, V);
        accum_kernel<<<NBUCKET, 512, 0, stream>>>(xTb, records, cursor, out);
        spill_kernel<<<256, 256, 0, stream>>>(xTb, spillRec, spillBkt, spillCnt,
                                              out);
    } else {
        hipMemsetAsync(out, 0, (size_t)out_size * sizeof(float), stream);
        direct_kernel<<<(V + 1) / 2, 256, 0, stream>>>(x, ht, sp, w, out, V, HW,
                                                       S, CH);
    }
}